// Round 9
// baseline (381.359 us; speedup 1.0000x reference)
//
#include <hip/hip_runtime.h>
#include <hip/hip_bf16.h>

typedef __attribute__((ext_vector_type(8))) short short8;
typedef __attribute__((ext_vector_type(4))) short short4v;
typedef __attribute__((ext_vector_type(4))) float float4v;
typedef __attribute__((address_space(3))) unsigned lds_u;
typedef __attribute__((address_space(1))) const unsigned gm_u;

__device__ __forceinline__ void a_copy16(void* lds, const void* g) {
    __builtin_amdgcn_global_load_lds((gm_u*)g, (lds_u*)lds, 16, 0, 0);
}

__device__ __forceinline__ float fast_exp2(float x) {
    return __builtin_amdgcn_exp2f(x);  // v_exp_f32 (base-2)
}

__device__ __forceinline__ unsigned short f2b(float f) {
    union { float f; unsigned u; } x; x.f = f;
    unsigned r = x.u + (0x7FFFu + ((x.u >> 16) & 1u));
    return (unsigned short)(r >> 16);
}
__device__ __forceinline__ float b2f(unsigned short u) {
    union { unsigned u; float f; } x; x.u = ((unsigned)u) << 16; return x.f;
}

// ---------------- prep: LDS-tiled weight transposes (coalesced both ways) + casts ----
struct PrepArgs {
    const float* src[10];
    unsigned short* dst[10];
    int K[10], N[10], mode[10];  // mode 0: 64x64-tiled transpose; 1: cvt4 (K = count)
    int bstart[11];
};
__global__ __launch_bounds__(256) void prep_w(PrepArgs a) {
    int bi = blockIdx.x;
    int s = 0;
    while (bi >= a.bstart[s + 1]) s++;
    bi -= a.bstart[s];
    const int t = threadIdx.x;
    if (a.mode[s]) {
        int i = bi * 256 + t;
        int n4 = a.K[s] >> 2;
        if (i >= n4) return;
        float4 v = ((const float4*)a.src[s])[i];
        short4v o;
        o[0] = (short)f2b(v.x); o[1] = (short)f2b(v.y);
        o[2] = (short)f2b(v.z); o[3] = (short)f2b(v.w);
        ((short4v*)a.dst[s])[i] = o;
        return;
    }
    __shared__ float tile[64][68];
    const int Kd = a.K[s], Nd = a.N[s];
    const int tilesK = Kd >> 6;
    const int tk = bi % tilesK, tn = bi / tilesK;
    {
        int r = t >> 2;
        const float* S = a.src[s] + (size_t)(tk * 64 + r) * Nd + tn * 64;
#pragma unroll
        for (int j = 0; j < 4; j++) {
            float4 v = ((const float4*)S)[(t & 3) + 4 * j];
            tile[r][(t & 3) * 4 + 16 * j] = v.x;
            tile[r][(t & 3) * 4 + 16 * j + 1] = v.y;
            tile[r][(t & 3) * 4 + 16 * j + 2] = v.z;
            tile[r][(t & 3) * 4 + 16 * j + 3] = v.w;
        }
    }
    __syncthreads();
    {
        int n = t >> 2, kc = (t & 3) * 16;
        unsigned short* D = a.dst[s] + (size_t)(tn * 64 + n) * Kd + tk * 64 + kc;
        short8 o0, o1;
#pragma unroll
        for (int j = 0; j < 8; j++) o0[j] = (short)f2b(tile[kc + j][n]);
#pragma unroll
        for (int j = 0; j < 8; j++) o1[j] = (short)f2b(tile[kc + 8 + j][n]);
        *(short8*)D = o0;
        *(short8*)(D + 8) = o1;
    }
}

// ---------------- dual V transpose: V[b*Tk,vstride] -> VT[b,h,d,Tk], key-permuted
// within each 64-key block: pos = c*4 + t  <=>  key = t*16 + c. Two jobs in one grid.
__global__ __launch_bounds__(256) void transpose_v2(const unsigned short* __restrict__ V0,
                                                    unsigned short* __restrict__ VT0, int vs0,
                                                    const unsigned short* __restrict__ V1,
                                                    unsigned short* __restrict__ VT1, int vs1,
                                                    int Tk, int nh, int nbh) {
    __shared__ unsigned short tile[64][72];
    const int tid = threadIdx.x;
    const int k0 = blockIdx.x * 64;
    int by = blockIdx.y;
    const unsigned short* V = V0;
    unsigned short* VT = VT0;
    int vstride = vs0;
    if (by >= nbh) { by -= nbh; V = V1; VT = VT1; vstride = vs1; }
    const int b = by / nh, h = by % nh;
    const unsigned short* Vb = V + ((size_t)b * Tk) * vstride + h * 64;
    int key = tid >> 2, dg = (tid & 3) * 16;
    const unsigned short* src = Vb + (size_t)(k0 + key) * vstride + dg;
    *(short8*)(&tile[key][dg]) = *(const short8*)src;
    *(short8*)(&tile[key][dg + 8]) = *(const short8*)(src + 8);
    __syncthreads();
    int d = tid >> 2, pg = (tid & 3) * 16;
    short8 o0, o1;
#pragma unroll
    for (int j = 0; j < 8; j++) {
        int pos = pg + j;
        o0[j] = (short)tile[((pos & 3) << 4) | (pos >> 2)][d];
    }
#pragma unroll
    for (int j = 0; j < 8; j++) {
        int pos = pg + 8 + j;
        o1[j] = (short)tile[((pos & 3) << 4) | (pos >> 2)][d];
    }
    unsigned short* dst = VT + ((size_t)by * 64 + d) * Tk + k0 + pg;
    *(short8*)dst = o0;
    *(short8*)(dst + 8) = o1;
}

// ---------------- dual-job GEMM 128x128 tile, BK=64, async LDS, swizzled ----------------
struct GJob {
    const unsigned short* A;
    const unsigned short* Bt;
    const float* blo;
    const float* bhi;
    int nsplit;
    unsigned short* C;
    int N;
    float qs;
    int ncut;
    int relu;
};
__global__ __launch_bounds__(256) void gemm128d(GJob j0, GJob j1, int tiles0, int M, int K) {
    GJob j = j0;
    int bx = blockIdx.x;
    if (bx >= tiles0) { j = j1; bx -= tiles0; }
    __shared__ unsigned short As[128 * 64];
    __shared__ unsigned short Bs[128 * 64];
    const int tid = threadIdx.x;
    const int bm = blockIdx.y * 128, bn = bx * 128;
    const int wave = tid >> 6, lane = tid & 63;
    const int wrow = (wave >> 1) * 64, wcol = (wave & 1) * 64;
    const int quad = lane >> 4, r16 = lane & 15;

    const unsigned short* aSrc[4];
    const unsigned short* bSrc[4];
#pragma unroll
    for (int i = 0; i < 4; i++) {
        int s = tid + 256 * i;
        int row = s >> 3, gl = ((s & 7) - row) & 7;
        aSrc[i] = j.A + (size_t)(bm + row) * K + gl * 8;
        bSrc[i] = j.Bt + (size_t)(bn + row) * K + gl * 8;
    }

    float4v zero4 = {0.0f, 0.0f, 0.0f, 0.0f};
    float4v acc[4][4];
#pragma unroll
    for (int i = 0; i < 4; i++)
#pragma unroll
        for (int jj = 0; jj < 4; jj++) acc[i][jj] = zero4;

    for (int k0 = 0; k0 < K; k0 += 64) {
#pragma unroll
        for (int i = 0; i < 4; i++) {
            a_copy16((char*)As + ((size_t)tid + 256 * i) * 16, aSrc[i] + k0);
            a_copy16((char*)Bs + ((size_t)tid + 256 * i) * 16, bSrc[i] + k0);
        }
        __syncthreads();
#pragma unroll
        for (int s = 0; s < 2; s++) {
            short8 af[4], bfr[4];
#pragma unroll
            for (int i = 0; i < 4; i++) {
                int r = wrow + i * 16 + r16;
                af[i] = *(const short8*)(As + r * 64 + ((s * 4 + quad + r) & 7) * 8);
            }
#pragma unroll
            for (int jj = 0; jj < 4; jj++) {
                int r = wcol + jj * 16 + r16;
                bfr[jj] = *(const short8*)(Bs + r * 64 + ((s * 4 + quad + r) & 7) * 8);
            }
#pragma unroll
            for (int i = 0; i < 4; i++)
#pragma unroll
                for (int jj = 0; jj < 4; jj++)
                    acc[i][jj] = __builtin_amdgcn_mfma_f32_16x16x32_bf16(af[i], bfr[jj], acc[i][jj], 0, 0, 0);
        }
        __syncthreads();
    }
#pragma unroll
    for (int jj = 0; jj < 4; jj++) {
        int n = bn + wcol + jj * 16 + r16;
        float bv = (n < j.nsplit) ? j.blo[n] : j.bhi[n - j.nsplit];
        float m_ = (n < j.ncut) ? j.qs : 1.0f;
#pragma unroll
        for (int i = 0; i < 4; i++) {
#pragma unroll
            for (int r = 0; r < 4; r++) {
                int m = bm + wrow + i * 16 + quad * 4 + r;
                float v = (acc[i][jj][r] + bv) * m_;
                if (j.relu) v = fmaxf(v, 0.0f);
                j.C[(size_t)m * j.N + n] = f2b(v);
            }
        }
    }
}

// ---------------- GEMM 64x128 tile, BK=64 (N=512 ops) ----------------
__global__ __launch_bounds__(256) void gemm64(const unsigned short* __restrict__ A,
                                              const unsigned short* __restrict__ Bt,
                                              const float* __restrict__ bias,
                                              unsigned short* __restrict__ C,
                                              int M, int N, int K, int relu,
                                              float qs, int ncut) {
    __shared__ unsigned short As[64 * 64];
    __shared__ unsigned short Bs[128 * 64];
    const int tid = threadIdx.x;
    const int bm = blockIdx.y * 64, bn = blockIdx.x * 128;
    const int wave = tid >> 6, lane = tid & 63;
    const int wrow = (wave >> 1) * 32, wcol = (wave & 1) * 64;
    const int quad = lane >> 4, r16 = lane & 15;

    const unsigned short* aSrc[2];
    const unsigned short* bSrc[4];
#pragma unroll
    for (int i = 0; i < 2; i++) {
        int s = tid + 256 * i;
        int row = s >> 3, gl = ((s & 7) - row) & 7;
        aSrc[i] = A + (size_t)(bm + row) * K + gl * 8;
    }
#pragma unroll
    for (int i = 0; i < 4; i++) {
        int s = tid + 256 * i;
        int row = s >> 3, gl = ((s & 7) - row) & 7;
        bSrc[i] = Bt + (size_t)(bn + row) * K + gl * 8;
    }

    float4v zero4 = {0.0f, 0.0f, 0.0f, 0.0f};
    float4v acc[2][4];
#pragma unroll
    for (int i = 0; i < 2; i++)
#pragma unroll
        for (int j = 0; j < 4; j++) acc[i][j] = zero4;

    for (int k0 = 0; k0 < K; k0 += 64) {
#pragma unroll
        for (int i = 0; i < 2; i++)
            a_copy16((char*)As + ((size_t)tid + 256 * i) * 16, aSrc[i] + k0);
#pragma unroll
        for (int i = 0; i < 4; i++)
            a_copy16((char*)Bs + ((size_t)tid + 256 * i) * 16, bSrc[i] + k0);
        __syncthreads();
#pragma unroll
        for (int s = 0; s < 2; s++) {
            short8 af[2], bfr[4];
#pragma unroll
            for (int i = 0; i < 2; i++) {
                int r = wrow + i * 16 + r16;
                af[i] = *(const short8*)(As + r * 64 + ((s * 4 + quad + r) & 7) * 8);
            }
#pragma unroll
            for (int j = 0; j < 4; j++) {
                int r = wcol + j * 16 + r16;
                bfr[j] = *(const short8*)(Bs + r * 64 + ((s * 4 + quad + r) & 7) * 8);
            }
#pragma unroll
            for (int i = 0; i < 2; i++)
#pragma unroll
                for (int j = 0; j < 4; j++)
                    acc[i][j] = __builtin_amdgcn_mfma_f32_16x16x32_bf16(af[i], bfr[j], acc[i][j], 0, 0, 0);
        }
        __syncthreads();
    }
#pragma unroll
    for (int j = 0; j < 4; j++) {
        int n = bn + wcol + j * 16 + r16;
        float bv = bias[n];
        float m_ = (n < ncut) ? qs : 1.0f;
#pragma unroll
        for (int i = 0; i < 2; i++) {
#pragma unroll
            for (int r = 0; r < 4; r++) {
                int m = bm + wrow + i * 16 + quad * 4 + r;
                float v = (acc[i][j][r] + bv) * m_;
                if (relu) v = fmaxf(v, 0.0f);
                C[(size_t)m * N + n] = f2b(v);
            }
        }
    }
}

// ---------------- flash attention v5 (reverted: 64-key chunks, 0-conflict swizzles) --
__global__ __launch_bounds__(256, 2) void attn5(const unsigned short* __restrict__ Q,
                                                const unsigned short* __restrict__ Kp,
                                                const unsigned short* __restrict__ VT,
                                                unsigned short* __restrict__ O,
                                                int Tq, int Tk, int qstride, int kstride,
                                                int ostride, int nh, int causal) {
    __shared__ unsigned short kt[2][64 * 64];
    __shared__ unsigned short vt[2][64 * 64];
    __shared__ unsigned short pt[4][32 * 64];
    const int tid = threadIdx.x;
    const int w = tid >> 6, lane = tid & 63;
    const int quad = lane >> 4, r16 = lane & 15;
    const int bh = blockIdx.y;
    const int b = bh / nh, head = bh % nh;
    int qt = blockIdx.x;
    if (causal && (bh & 16)) qt = (gridDim.x - 1) - qt;  // causal load balance
    const int qw = qt * 128 + w * 32;
    const unsigned short* Qb = Q + ((size_t)b * Tq) * qstride + head * 64;
    const unsigned short* Kb = Kp + ((size_t)b * Tk) * kstride + head * 64;
    const unsigned short* VTb = VT + ((size_t)bh * 64) * Tk;
    unsigned short* Ob = O + ((size_t)b * Tq) * ostride + head * 64;
    unsigned short* ptw = pt[w];

    const unsigned short* kSrc[2];
    const unsigned short* vSrc[2];
#pragma unroll
    for (int i = 0; i < 2; i++) {
        int s = tid + 256 * i;
        int row = s >> 3, lg = ((s & 7) - row) & 7;
        kSrc[i] = Kb + (size_t)row * kstride + lg * 8;
        vSrc[i] = VTb + (size_t)row * Tk + lg * 8;
    }
    auto issue = [&](int buf, int k0) {
#pragma unroll
        for (int i = 0; i < 2; i++) {
            a_copy16((char*)(&kt[buf][0]) + ((size_t)tid + 256 * i) * 16,
                     kSrc[i] + (size_t)k0 * kstride);
            a_copy16((char*)(&vt[buf][0]) + ((size_t)tid + 256 * i) * 16, vSrc[i] + k0);
        }
    };

    short8 aq[2][2];
#pragma unroll
    for (int qs = 0; qs < 2; qs++)
#pragma unroll
        for (int ks = 0; ks < 2; ks++)
            aq[qs][ks] = *(const short8*)(Qb + (size_t)(qw + qs * 16 + r16) * qstride + ks * 32 + quad * 8);

    short8 ones8;
#pragma unroll
    for (int j = 0; j < 8; j++) ones8[j] = (short)0x3F80;  // bf16 1.0

    float4v zero4 = {0.0f, 0.0f, 0.0f, 0.0f};
    float4v oacc[2][4], lacc[2];
#pragma unroll
    for (int qs = 0; qs < 2; qs++) {
        lacc[qs] = zero4;
#pragma unroll
        for (int nt = 0; nt < 4; nt++) oacc[qs][nt] = zero4;
    }

    const int kmax = causal ? (qt * 128 + 128) : Tk;
    issue(0, 0);
    for (int k0 = 0, buf = 0; k0 < kmax; k0 += 64, buf ^= 1) {
        __syncthreads();  // drains prefetch vmcnt; buf ready
        if (k0 + 64 < kmax) issue(buf ^ 1, k0 + 64);
        if (!(causal && k0 > qw + 31)) {
            float4v sacc[2][4];
#pragma unroll
            for (int t = 0; t < 4; t++) {
                int row = t * 16 + r16;
                short8 b0 = *(const short8*)(&kt[buf][row * 64 + ((quad + row) & 7) * 8]);
                short8 b1 = *(const short8*)(&kt[buf][row * 64 + ((4 + quad + row) & 7) * 8]);
#pragma unroll
                for (int qs = 0; qs < 2; qs++) {
                    float4v z = zero4;
                    z = __builtin_amdgcn_mfma_f32_16x16x32_bf16(aq[qs][0], b0, z, 0, 0, 0);
                    z = __builtin_amdgcn_mfma_f32_16x16x32_bf16(aq[qs][1], b1, z, 0, 0, 0);
                    sacc[qs][t] = z;
                }
            }
            const bool diag = causal && (k0 + 63 > qw);
            if (diag) {
#pragma unroll
                for (int qs = 0; qs < 2; qs++) {
#pragma unroll
                    for (int r = 0; r < 4; r++) {
                        const int row = qs * 16 + quad * 4 + r;
                        const int qrow = qw + row;
                        float p[4];
#pragma unroll
                        for (int t = 0; t < 4; t++)
                            p[t] = ((k0 + t * 16 + r16) > qrow) ? 0.0f : fast_exp2(sacc[qs][t][r]);
                        union { __hip_bfloat162 h; unsigned u; } a01, a23;
                        a01.h = __float22bfloat162_rn(make_float2(p[0], p[1]));
                        a23.h = __float22bfloat162_rn(make_float2(p[2], p[3]));
                        union { unsigned u2[2]; short4v s4; } pk;
                        pk.u2[0] = a01.u;
                        pk.u2[1] = a23.u;
                        *(short4v*)(&ptw[row * 64 + (r16 ^ ((row & 7) << 1)) * 4]) = pk.s4;
                    }
                }
            } else {
#pragma unroll
                for (int qs = 0; qs < 2; qs++) {
#pragma unroll
                    for (int r = 0; r < 4; r++) {
                        const int row = qs * 16 + quad * 4 + r;
                        float p0 = fast_exp2(sacc[qs][0][r]);
                        float p1 = fast_exp2(sacc[qs][1][r]);
                        float p2 = fast_exp2(sacc[qs][2][r]);
                        float p3 = fast_exp2(sacc[qs][3][r]);
                        union { __hip_bfloat162 h; unsigned u; } a01, a23;
                        a01.h = __float22bfloat162_rn(make_float2(p0, p1));
                        a23.h = __float22bfloat162_rn(make_float2(p2, p3));
                        union { unsigned u2[2]; short4v s4; } pk;
                        pk.u2[0] = a01.u;
                        pk.u2[1] = a23.u;
                        *(short4v*)(&ptw[row * 64 + (r16 ^ ((row & 7) << 1)) * 4]) = pk.s4;
                    }
                }
            }
#pragma unroll
            for (int ks = 0; ks < 2; ks++) {
                short8 vb[4];
#pragma unroll
                for (int nt = 0; nt < 4; nt++) {
                    int row = nt * 16 + r16;
                    vb[nt] = *(const short8*)(&vt[buf][row * 64 + ((ks * 4 + quad + row) & 7) * 8]);
                }
#pragma unroll
                for (int qs = 0; qs < 2; qs++) {
                    int row = qs * 16 + r16;
                    int h = (ks * 8 + quad * 2) ^ ((row & 7) << 1);
                    short8 ap = *(const short8*)(&ptw[row * 64 + h * 4]);
#pragma unroll
                    for (int nt = 0; nt < 4; nt++)
                        oacc[qs][nt] = __builtin_amdgcn_mfma_f32_16x16x32_bf16(ap, vb[nt], oacc[qs][nt], 0, 0, 0);
                    lacc[qs] = __builtin_amdgcn_mfma_f32_16x16x32_bf16(ap, ones8, lacc[qs], 0, 0, 0);
                }
            }
        }
    }
#pragma unroll
    for (int qs = 0; qs < 2; qs++)
#pragma unroll
        for (int r = 0; r < 4; r++) {
            const int qrow = qw + qs * 16 + quad * 4 + r;
            unsigned short* orow = Ob + (size_t)qrow * ostride;
            const float inv = 1.0f / lacc[qs][r];
#pragma unroll
            for (int nt = 0; nt < 4; nt++)
                orow[nt * 16 + r16] = f2b(oacc[qs][nt][r] * inv);
        }
}

// ---------------- fused residual + LayerNorm: one WAVE per row (no LDS/barrier) ------
__global__ __launch_bounds__(256) void add_ln(const unsigned short* __restrict__ X,
                                              const unsigned short* __restrict__ Rb,
                                              const float* __restrict__ Rf,
                                              const float* __restrict__ g,
                                              const float* __restrict__ bta,
                                              unsigned short* __restrict__ outb,
                                              float* __restrict__ outf) {
    const int row = blockIdx.x * 4 + (threadIdx.x >> 6);
    const int lane = threadIdx.x & 63;
    short8 xv = *(const short8*)(X + (size_t)row * 512 + lane * 8);
    float v[8];
    if (Rb) {
        short8 rv = *(const short8*)(Rb + (size_t)row * 512 + lane * 8);
#pragma unroll
        for (int j = 0; j < 8; j++) v[j] = b2f((unsigned short)xv[j]) + b2f((unsigned short)rv[j]);
    } else {
        float4 r0 = ((const float4*)(Rf + (size_t)row * 512))[lane * 2];
        float4 r1 = ((const float4*)(Rf + (size_t)row * 512))[lane * 2 + 1];
        v[0] = b2f((unsigned short)xv[0]) + r0.x;
        v[1] = b2f((unsigned short)xv[1]) + r0.y;
        v[2] = b2f((unsigned short)xv[2]) + r0.z;
        v[3] = b2f((unsigned short)xv[3]) + r0.w;
        v[4] = b2f((unsigned short)xv[4]) + r1.x;
        v[5] = b2f((unsigned short)xv[5]) + r1.y;
        v[6] = b2f((unsigned short)xv[6]) + r1.z;
        v[7] = b2f((unsigned short)xv[7]) + r1.w;
    }
    float s = 0.0f, ss = 0.0f;
#pragma unroll
    for (int j = 0; j < 8; j++) { s += v[j]; ss += v[j] * v[j]; }
#pragma unroll
    for (int off = 32; off > 0; off >>= 1) {
        s += __shfl_xor(s, off, 64);
        ss += __shfl_xor(ss, off, 64);
    }
    float mean = s * (1.0f / 512.0f);
    float var = ss * (1.0f / 512.0f) - mean * mean;
    float rstd = rsqrtf(var + 1e-5f);
    float4 g0 = ((const float4*)g)[lane * 2], g1 = ((const float4*)g)[lane * 2 + 1];
    float4 b0 = ((const float4*)bta)[lane * 2], b1 = ((const float4*)bta)[lane * 2 + 1];
    float o[8];
    o[0] = (v[0] - mean) * rstd * g0.x + b0.x;
    o[1] = (v[1] - mean) * rstd * g0.y + b0.y;
    o[2] = (v[2] - mean) * rstd * g0.z + b0.z;
    o[3] = (v[3] - mean) * rstd * g0.w + b0.w;
    o[4] = (v[4] - mean) * rstd * g1.x + b1.x;
    o[5] = (v[5] - mean) * rstd * g1.y + b1.y;
    o[6] = (v[6] - mean) * rstd * g1.z + b1.z;
    o[7] = (v[7] - mean) * rstd * g1.w + b1.w;
    if (outb) {
        short8 ob;
#pragma unroll
        for (int j = 0; j < 8; j++) ob[j] = (short)f2b(o[j]);
        *(short8*)(outb + (size_t)row * 512 + lane * 8) = ob;
    }
    if (outf) {
        float4* of = (float4*)(outf + (size_t)row * 512);
        of[lane * 2] = make_float4(o[0], o[1], o[2], o[3]);
        of[lane * 2 + 1] = make_float4(o[4], o[5], o[6], o[7]);
    }
}

extern "C" void kernel_launch(void* const* d_in, const int* in_sizes, int n_in,
                              void* d_out, int out_size, void* d_ws, size_t ws_size,
                              hipStream_t stream) {
    const int E = 512, FF = 1536, B = 4, Ct = 2048, H = 8;
    const int M = B * Ct;  // 8192
    const float* word_vec = (const float*)d_in[0];
    const float* enc = (const float*)d_in[1];
    const float* qkv_w = (const float*)d_in[4];
    const float* qkv_b = (const float*)d_in[5];
    const float* sa_w = (const float*)d_in[6];
    const float* sa_b = (const float*)d_in[7];
    const float* q_w = (const float*)d_in[8];
    const float* q_b = (const float*)d_in[9];
    const float* k_b_ = (const float*)d_in[11];
    const float* k_w = (const float*)d_in[10];
    const float* v_w = (const float*)d_in[12];
    const float* v_b = (const float*)d_in[13];
    const float* ca_w = (const float*)d_in[14];
    const float* ca_b = (const float*)d_in[15];
    const float* ff1_w = (const float*)d_in[16];
    const float* ff1_b = (const float*)d_in[17];
    const float* ff2_w = (const float*)d_in[18];
    const float* ff2_b = (const float*)d_in[19];
    const float* ln1_g = (const float*)d_in[20];
    const float* ln1_b = (const float*)d_in[21];
    const float* ln2_g = (const float*)d_in[22];
    const float* ln2_b = (const float*)d_in[23];
    const float* ln3_g = (const float*)d_in[24];
    const float* ln3_b = (const float*)d_in[25];
    (void)in_sizes; (void)n_in; (void)out_size; (void)ws_size;

    char* base = (char*)d_ws;
    size_t off = 0;
    auto alloc = [&](size_t bytes) { char* p = base + off; off += (bytes + 255) & ~(size_t)255; return p; };
    unsigned short* Wqkv = (unsigned short*)alloc((size_t)FF * E * 2);
    unsigned short* Wsa = (unsigned short*)alloc((size_t)E * E * 2);
    unsigned short* Wq = (unsigned short*)alloc((size_t)E * E * 2);
    unsigned short* WkWv = (unsigned short*)alloc((size_t)2 * E * E * 2);  // [1024,512]
    unsigned short* Wca = (unsigned short*)alloc((size_t)E * E * 2);
    unsigned short* Wf1 = (unsigned short*)alloc((size_t)FF * E * 2);
    unsigned short* Wf2 = (unsigned short*)alloc((size_t)FF * E * 2);
    unsigned short* BIG = (unsigned short*)alloc((size_t)M * FF * 2);   // qkv / q2 / ff1out
    unsigned short* KVc = (unsigned short*)alloc((size_t)M * 2 * E * 2);  // cross [K|V]
    unsigned short* AO = (unsigned short*)alloc((size_t)M * E * 2);     // sa-out -> X1b
    unsigned short* Xb = (unsigned short*)alloc((size_t)M * E * 2);     // bf16 word_vec -> X2b
    unsigned short* Eb = (unsigned short*)alloc((size_t)M * E * 2);     // bf16 enc -> ca-out
    unsigned short* VTs = (unsigned short*)alloc((size_t)M * E * 2);    // self V^T
    unsigned short* VTc = (unsigned short*)alloc((size_t)M * E * 2);    // cross V^T
    unsigned short* PRb = (unsigned short*)alloc((size_t)M * E * 2);    // pre-LN bf16
    float* out = (float*)d_out;

    dim3 blk(256);

    PrepArgs pa;
    const float* srcs[10] = {qkv_w, sa_w, q_w, k_w, v_w, ca_w, ff1_w, ff2_w, word_vec, enc};
    unsigned short* dsts[10] = {Wqkv, Wsa, Wq, WkWv, WkWv + (size_t)E * E, Wca, Wf1, Wf2, Xb, Eb};
    int Ks[10] = {E, E, E, E, E, E, E, FF, M * E, M * E};
    int Ns[10] = {3 * E, E, E, E, E, E, FF, E, 1, 1};
    int modes[10] = {0, 0, 0, 0, 0, 0, 0, 0, 1, 1};
    int cum = 0;
    for (int i = 0; i < 10; i++) {
        pa.src[i] = srcs[i]; pa.dst[i] = dsts[i]; pa.K[i] = Ks[i]; pa.N[i] = Ns[i];
        pa.mode[i] = modes[i];
        pa.bstart[i] = cum;
        int items = modes[i] ? ((Ks[i] / 4 + 255) / 256) : ((Ks[i] / 64) * (Ns[i] / 64));
        cum += items;
    }
    pa.bstart[10] = cum;
    prep_w<<<dim3(cum), blk, 0, stream>>>(pa);

    const float SC = 0.125f * 1.44269504f;  // 1/sqrt(64) * log2(e), folded into Q
    GJob jQKV = {Xb, Wqkv, qkv_b, qkv_b, 3 * E, BIG, 3 * E, SC, E, 0};
    GJob jKV = {Eb, WkWv, k_b_, v_b, E, KVc, 2 * E, 1.0f, 0, 0};
    GJob jFF1 = {Xb, Wf1, ff1_b, ff1_b, FF, BIG, FF, 1.0f, 0, 1};

    // ---- projections that depend only on prep: QKV (12 tiles) + cross KV (8 tiles) ----
    gemm128d<<<dim3(20, 64), blk, 0, stream>>>(jQKV, jKV, 12, M, E);
    // ---- both V transposes in one dispatch ----
    transpose_v2<<<dim3(Ct / 64, 2 * B * H), blk, 0, stream>>>(
        BIG + 2 * E, VTs, 3 * E, KVc + E, VTc, 2 * E, Ct, H, B * H);
    // ---- self-attention ----
    attn5<<<dim3(Ct / 128, B * H), blk, 0, stream>>>(BIG, BIG + E, VTs, AO,
                                                     Ct, Ct, 3 * E, 3 * E, E, H, 1);
    gemm64<<<dim3(4, 128), blk, 0, stream>>>(AO, Wsa, sa_b, PRb, M, E, E, 0, 1.0f, 0);
    add_ln<<<dim3(M / 4), blk, 0, stream>>>(PRb, nullptr, word_vec, ln1_g, ln1_b, AO, nullptr);
    // ---- cross-attention (only Q-proj on the critical path) ----
    unsigned short* Q2 = BIG;  // qkv consumed; reuse as [M,512]
    gemm64<<<dim3(4, 128), blk, 0, stream>>>(AO, Wq, q_b, Q2, M, E, E, 0, SC, E);
    attn5<<<dim3(Ct / 128, B * H), blk, 0, stream>>>(Q2, KVc, VTc, Eb,
                                                     Ct, Ct, E, 2 * E, E, H, 0);
    gemm64<<<dim3(4, 128), blk, 0, stream>>>(Eb, Wca, ca_b, PRb, M, E, E, 0, 1.0f, 0);
    add_ln<<<dim3(M / 4), blk, 0, stream>>>(PRb, AO, nullptr, ln2_g, ln2_b, Xb, nullptr);
    // ---- feed-forward ----
    gemm128d<<<dim3(12, 64), blk, 0, stream>>>(jFF1, jFF1, 12, M, E);
    gemm64<<<dim3(4, 128), blk, 0, stream>>>(BIG, Wf2, ff2_b, PRb, M, E, FF, 0, 1.0f, 0);
    add_ln<<<dim3(M / 4), blk, 0, stream>>>(PRb, Xb, nullptr, ln3_g, ln3_b, nullptr, out);
}